// Round 3
// baseline (1087.119 us; speedup 1.0000x reference)
//
#include <hip/hip_runtime.h>
#include <stdint.h>

typedef __bf16 bf16;
typedef __attribute__((ext_vector_type(8))) __bf16 bf16x8;
typedef __attribute__((ext_vector_type(4))) float f32x4;
typedef unsigned short u16;
typedef unsigned int u32;

#define B_TOK 4096
#define D_IN  1024
#define D_HID 4096
#define D_OUT 1024
#define NE    8
#define KTOT  (NE * D_HID)   // 32768

#define AS1 __attribute__((address_space(1)))
#define AS3 __attribute__((address_space(3)))

// fp32 -> bf16 round-to-nearest-even
__device__ __forceinline__ u16 f2bf(float f) {
  u32 u = __float_as_uint(f);
  return (u16)((u + 0x7FFFu + ((u >> 16) & 1u)) >> 16);
}
__device__ __forceinline__ u32 pack2(float a, float b) {
  return (u32)f2bf(a) | ((u32)f2bf(b) << 16);
}

// ---------------- convert fp32 -> bf16 (contiguous) ----------------
__global__ __launch_bounds__(256) void cvt_bf16_kernel(const float* __restrict__ in,
                                                       u32* __restrict__ out, long n) {
  long i = ((long)blockIdx.x * 256 + threadIdx.x) * 8;
  if (i >= n) return;
  const float4* pf = (const float4*)(in + i);
  float4 f0 = pf[0], f1 = pf[1];
  uint4 o = make_uint4(pack2(f0.x, f0.y), pack2(f0.z, f0.w),
                       pack2(f1.x, f1.y), pack2(f1.z, f1.w));
  *(uint4*)(out + i / 2) = o;
}

// ------- batched transpose + convert: in[z][R][C] f32 -> out[z][C][R] bf16 -------
__global__ __launch_bounds__(256) void transpose_bf16_kernel(const float* __restrict__ in,
                                                             u16* __restrict__ out,
                                                             int R, int C) {
  __shared__ u16 tileT[64][68];   // [col-of-in][row-of-in]
  const size_t bo = (size_t)blockIdx.z * R * C;
  const int c0 = blockIdx.x * 64, r0 = blockIdx.y * 64;
  const int tid = threadIdx.x;
  const int lr = tid >> 4;           // 0..15
  const int lc = (tid & 15) * 4;     // 0..60
#pragma unroll
  for (int p = 0; p < 4; ++p) {
    const int r = p * 16 + lr;
    const float4 v = *(const float4*)(in + bo + (size_t)(r0 + r) * C + c0 + lc);
    tileT[lc + 0][r] = f2bf(v.x);
    tileT[lc + 1][r] = f2bf(v.y);
    tileT[lc + 2][r] = f2bf(v.z);
    tileT[lc + 3][r] = f2bf(v.w);
  }
  __syncthreads();
  const int oc  = tid >> 3;          // 0..31
  const int och = (tid & 7) * 8;     // 0..56
#pragma unroll
  for (int p = 0; p < 2; ++p) {
    const int c = p * 32 + oc;
    bf16x8 v = *(const bf16x8*)(&tileT[c][och]);
    *(bf16x8*)(out + bo + (size_t)(c0 + c) * R + r0 + och) = v;
  }
}

// ---------------- 256x256 MFMA GEMM, BK=32, 4-buffer deep pipeline ----------------
// C[m,n] (+)= sum_k A[m,k] * Bt[n,k]
// MODE 0: gating L1  : C = bf16( relu(acc + bias[n]) ),               grid (16,16,1)
// MODE 1: expert L1  : C = bf16( gate[m,e] * relu(acc + bias[e,n]) ), grid (16,16,E)
// MODE 2: final      : atomicAdd fp32 C += acc (split-K over z),      grid (16,4,4)
// 512 thr = 8 waves (2M x 4N), per-wave output 128x64, acc 8x4 f32x4.
// LDS 128 KB = 4 buffers x (A 256x32 | B 256x32) bf16 -> prefetch 3 tiles ahead
// (issue-to-wait cover ~6 phases; vmcnt(10) steady state, never 0 in main loop;
//  epilogue peel drains 8 -> 4 -> 0).
// Phases per tile = 2 (16 MFMA each, one K-step of 32), 2 barriers per phase.
// XOR swizzle: LDS slot (row, s) holds global k-chunk s ^ ((row>>1)&3);
// folded into the staging lane->global map; reads are 2-way bank alias (free).
// Block swizzle: XCD-chunked (bijective, nwg%8==0): MODE1 -> one expert per XCD
// (xb + W1t[e] L2-resident per XCD); MODE0/2 -> contiguous n-panels per XCD.
template<int MODE>
__global__ __launch_bounds__(512, 2) void gemm_mfma256(
    const bf16* __restrict__ A,
    const bf16* __restrict__ Bt,
    const float* __restrict__ bias,
    const float* __restrict__ gate,
    void* __restrict__ Cptr,
    int K, long ldB, long kOffB, long ldC, int kIters, int eArg)
{
  __shared__ __align__(16) bf16 smem[65536];   // 128 KB = 4 x 32KB buffers

  const int tid  = threadIdx.x;
  const int wave = tid >> 6;
  const int lane = tid & 63;
  const int quad = lane >> 4;
  const int l16  = lane & 15;
  const int wr = (wave >> 2) * 128;   // wave row base in 256-tile
  const int wc = (wave & 3) * 64;     // wave col base

  // XCD-chunked block swizzle (all grids have nwg % 8 == 0)
  const int gx = gridDim.x, gy = gridDim.y;
  const int nwg = gx * gy * gridDim.z;
  const int orig = blockIdx.x + gx * (blockIdx.y + gy * blockIdx.z);
  const int cid = (orig & 7) * (nwg >> 3) + (orig >> 3);
  const int bx = cid % gx;
  const int rest = cid / gx;
  const int by = rest % gy;
  const int bz = rest / gy;

  const int m0 = bx * 256;
  const int n0 = by * 256;

  int expert = 0;
  long cColOff = 0;
  const bf16* Bp = Bt;
  const float* biasP = bias;
  if (MODE == 1) {
    if (gridDim.z > 1) { expert = bz; cColOff = (long)expert * D_HID; }
    else               { expert = eArg; }
    Bp = Bt + (size_t)expert * D_HID * (size_t)ldB;
    biasP = bias + (size_t)expert * D_HID;
  }
  const int nt = kIters;                                  // K-tiles of 32
  const long kBase = (MODE == 2) ? (long)bz * nt * 32 : 0;

  // staging: per gload instr 64 lanes x 16B = 16 rows of 64B.
  // lane -> row (lane>>2), LDS slot lane&3; global chunk = slot ^ ((row>>1)&3).
  const int sRow = lane >> 2;                       // 0..15
  const int sCol = ((lane & 3) ^ ((lane >> 3) & 3)) * 8;  // pre-swizzled k-chunk

  const bf16* aSrc = A  + (size_t)(m0 + wave * 32 + sRow) * K   + kBase + sCol;
  const bf16* bSrc = Bp + (size_t)(n0 + wave * 32 + sRow) * ldB + kOffB + kBase + sCol;

  // ds_read offsets (elems), loop-invariant: slot = quad ^ ((row>>1)&3)
  const int xorv = (quad ^ ((l16 >> 1) & 3)) * 8;
  int aOff[8], bOff[4];
#pragma unroll
  for (int i = 0; i < 8; ++i) aOff[i] = (wr + i * 16 + l16) * 32 + xorv;
#pragma unroll
  for (int j = 0; j < 4; ++j) bOff[j] = (wc + j * 16 + l16) * 32 + xorv;

  f32x4 acc[8][4];
#pragma unroll
  for (int i = 0; i < 8; ++i)
#pragma unroll
    for (int j = 0; j < 4; ++j)
      acc[i][j] = (f32x4){0.f, 0.f, 0.f, 0.f};

#define GLLA(tt, bb) do { \
    bf16* d_ = smem + (bb) * 16384 + wave * 1024; \
    const bf16* s_ = aSrc + (size_t)(tt) * 32; \
    __builtin_amdgcn_global_load_lds((AS1 void*)(s_), (AS3 void*)(d_), 16, 0, 0); \
    __builtin_amdgcn_global_load_lds((AS1 void*)(s_ + (size_t)16 * K), (AS3 void*)(d_ + 512), 16, 0, 0); \
  } while (0)
#define GLLB(tt, bb) do { \
    bf16* d_ = smem + (bb) * 16384 + 8192 + wave * 1024; \
    const bf16* s_ = bSrc + (size_t)(tt) * 32; \
    __builtin_amdgcn_global_load_lds((AS1 void*)(s_), (AS3 void*)(d_), 16, 0, 0); \
    __builtin_amdgcn_global_load_lds((AS1 void*)(s_ + (size_t)16 * ldB), (AS3 void*)(d_ + 512), 16, 0, 0); \
  } while (0)

// One K-tile: P0 {issue A(t+3); wait vmcnt; barrier; read B+A(m0-3); lgkm0; 16 MFMA; barrier}
//             P1 {read A(m4-7); issue B(t+3); barrier; lgkm0; 16 MFMA; barrier}
#define TILE_BODY(T, VMW, ISS) do { \
    const bf16* Ab_ = smem + ((T) & 3) * 16384; \
    const bf16* Bb_ = Ab_ + 8192; \
    bf16x8 af_[4], bf_[4]; \
    if (ISS) GLLA((T) + 3, ((T) + 3) & 3); \
    asm volatile("s_waitcnt vmcnt(" #VMW ")"); \
    __builtin_amdgcn_s_barrier(); \
    __builtin_amdgcn_sched_barrier(0); \
    _Pragma("unroll") \
    for (int j_ = 0; j_ < 4; ++j_) bf_[j_] = *(const bf16x8*)(Bb_ + bOff[j_]); \
    _Pragma("unroll") \
    for (int i_ = 0; i_ < 4; ++i_) af_[i_] = *(const bf16x8*)(Ab_ + aOff[i_]); \
    asm volatile("s_waitcnt lgkmcnt(0)"); \
    __builtin_amdgcn_sched_barrier(0); \
    __builtin_amdgcn_s_setprio(1); \
    _Pragma("unroll") \
    for (int i_ = 0; i_ < 4; ++i_) \
      _Pragma("unroll") \
      for (int j_ = 0; j_ < 4; ++j_) \
        acc[i_][j_] = __builtin_amdgcn_mfma_f32_16x16x32_bf16(af_[i_], bf_[j_], acc[i_][j_], 0, 0, 0); \
    __builtin_amdgcn_s_setprio(0); \
    __builtin_amdgcn_s_barrier(); \
    _Pragma("unroll") \
    for (int i_ = 0; i_ < 4; ++i_) af_[i_] = *(const bf16x8*)(Ab_ + aOff[4 + i_]); \
    if (ISS) GLLB((T) + 3, ((T) + 3) & 3); \
    __builtin_amdgcn_s_barrier(); \
    asm volatile("s_waitcnt lgkmcnt(0)"); \
    __builtin_amdgcn_sched_barrier(0); \
    __builtin_amdgcn_s_setprio(1); \
    _Pragma("unroll") \
    for (int i_ = 0; i_ < 4; ++i_) \
      _Pragma("unroll") \
      for (int j_ = 0; j_ < 4; ++j_) \
        acc[4 + i_][j_] = __builtin_amdgcn_mfma_f32_16x16x32_bf16(af_[i_], bf_[j_], acc[4 + i_][j_], 0, 0, 0); \
    __builtin_amdgcn_s_setprio(0); \
    __builtin_amdgcn_s_barrier(); \
  } while (0)

  // prologue: stage tiles 0,1,2 (12 loads in flight)
  GLLA(0, 0); GLLB(0, 0);
  GLLA(1, 1); GLLB(1, 1);
  GLLA(2, 2); GLLB(2, 2);

  int t = 0;
  for (; t < nt - 3; ++t) TILE_BODY(t, 10, 1);
  TILE_BODY(t, 8, 0); ++t;
  TILE_BODY(t, 4, 0); ++t;
  TILE_BODY(t, 0, 0);

#undef GLLA
#undef GLLB
#undef TILE_BODY

  // epilogue: C/D layout col = lane&15, row = quad*4 + reg
  if (MODE <= 1) {
    const int SL = 72;
    u16* slab = (u16*)smem + wave * (16 * SL);
    u16* C = (u16*)Cptr;
    float bv[4];
#pragma unroll
    for (int j = 0; j < 4; ++j) bv[j] = biasP[n0 + wc + j * 16 + l16];
#pragma unroll
    for (int i = 0; i < 8; ++i) {
#pragma unroll
      for (int r = 0; r < 4; ++r) {
        const int lrow = quad * 4 + r;
        float sc = 1.0f;
        if (MODE == 1) sc = gate[(size_t)(m0 + wr + i * 16 + lrow) * NE + expert];
#pragma unroll
        for (int j = 0; j < 4; ++j) {
          float v = fmaxf(acc[i][j][r] + bv[j], 0.0f) * sc;
          slab[lrow * SL + j * 16 + l16] = f2bf(v);
        }
      }
      const int rrow = lane & 15;
      const int c0c  = lane >> 4;
      bf16x8 v0 = *(const bf16x8*)(slab + rrow * SL + c0c * 8);
      bf16x8 v1 = *(const bf16x8*)(slab + rrow * SL + (c0c + 4) * 8);
      u16* orow = C + (size_t)(m0 + wr + i * 16 + rrow) * ldC + cColOff + n0 + wc;
      *(bf16x8*)(orow + c0c * 8)       = v0;
      *(bf16x8*)(orow + (c0c + 4) * 8) = v1;
    }
  } else {
    float* C = (float*)Cptr;
#pragma unroll
    for (int i = 0; i < 8; ++i) {
#pragma unroll
      for (int r = 0; r < 4; ++r) {
        const int row = m0 + wr + i * 16 + quad * 4 + r;
        float* crow = C + (size_t)row * ldC + n0 + wc + l16;
#pragma unroll
        for (int j = 0; j < 4; ++j)
          atomicAdd(crow + j * 16, acc[i][j][r]);
      }
    }
  }
}

// ---------------- gating layer 2 + softmax: one wave per row ----------------
__global__ __launch_bounds__(256) void gate_softmax_kernel(const bf16* __restrict__ g,
                                                           const float* __restrict__ Wg2,
                                                           const float* __restrict__ bg2,
                                                           float* __restrict__ gate) {
  const int wave = threadIdx.x >> 6, lane = threadIdx.x & 63;
  const int row = blockIdx.x * 4 + wave;
  const bf16* gr = g + (size_t)row * D_HID;
  float acc[NE];
#pragma unroll
  for (int e = 0; e < NE; ++e) acc[e] = 0.f;
  for (int k = lane; k < D_HID; k += 64) {
    const float gv = (float)gr[k];
    const float* w = Wg2 + (size_t)k * NE;
#pragma unroll
    for (int e = 0; e < NE; ++e) acc[e] += gv * w[e];
  }
#pragma unroll
  for (int e = 0; e < NE; ++e) {
    float v = acc[e];
#pragma unroll
    for (int off = 32; off > 0; off >>= 1) v += __shfl_down(v, off);
    acc[e] = v;
  }
  if (lane == 0) {
    float mx = -3.4e38f;
#pragma unroll
    for (int e = 0; e < NE; ++e) { acc[e] += bg2[e]; mx = fmaxf(mx, acc[e]); }
    float s = 0.f;
#pragma unroll
    for (int e = 0; e < NE; ++e) { acc[e] = __expf(acc[e] - mx); s += acc[e]; }
    const float inv = 1.f / s;
#pragma unroll
    for (int e = 0; e < NE; ++e) gate[(size_t)row * NE + e] = acc[e] * inv;
  }
}

// ---------------- out = sum_e gate[b,e] * b2[e,o]  (WRITES out) -------------
__global__ __launch_bounds__(256) void gate_bias_kernel(const float* __restrict__ gate,
                                                        const float* __restrict__ b2,
                                                        float* __restrict__ out) {
  const int idx = blockIdx.x * 256 + threadIdx.x;
  const int b = idx >> 8;
  const int o = (idx & 255) * 4;
  float4 v = {0.f, 0.f, 0.f, 0.f};
#pragma unroll
  for (int e = 0; e < NE; ++e) {
    const float gv = gate[(size_t)b * NE + e];
    const float4 bb = *(const float4*)(b2 + (size_t)e * D_OUT + o);
    v.x += gv * bb.x; v.y += gv * bb.y; v.z += gv * bb.z; v.w += gv * bb.w;
  }
  *(float4*)(out + (size_t)b * D_OUT + o) = v;
}

extern "C" void kernel_launch(void* const* d_in, const int* in_sizes, int n_in,
                              void* d_out, int out_size, void* d_ws, size_t ws_size,
                              hipStream_t stream) {
  const float* x   = (const float*)d_in[0];   // [4096,1024]
  const float* W1  = (const float*)d_in[1];   // [8,1024,4096]
  const float* b1  = (const float*)d_in[2];   // [8,4096]
  const float* W2  = (const float*)d_in[3];   // [8,4096,1024] == [32768,1024]
  const float* b2  = (const float*)d_in[4];   // [8,1024]
  const float* Wg1 = (const float*)d_in[5];   // [1024,4096]
  const float* bg1 = (const float*)d_in[6];   // [4096]
  const float* Wg2 = (const float*)d_in[7];   // [4096,8]
  const float* bg2 = (const float*)d_in[8];   // [8]
  float* out = (float*)d_out;                 // [4096,1024] fp32

  char* p = (char*)d_ws;
  bf16* xb   = (bf16*)p; p += (size_t)B_TOK * D_IN * 2;        //  8.4 MB
  bf16* Wg1t = (bf16*)p; p += (size_t)D_HID * D_IN * 2;        //  8.4 MB [4096,1024]
  bf16* W1t  = (bf16*)p; p += (size_t)NE * D_HID * D_IN * 2;   // 67 MB   [8][4096,1024]
  bf16* W2t  = (bf16*)p; p += (size_t)D_OUT * KTOT * 2;        // 67 MB   [1024,32768]
  bf16* g    = (bf16*)p; p += (size_t)B_TOK * D_HID * 2;       // 33.5 MB
  float* gate= (float*)p; p += (size_t)B_TOK * NE * 4;         //  0.13 MB
  bf16* hs   = (bf16*)p;                                       // big: 268 MB / small: 33.5 MB
  const size_t fixed = (size_t)(p - (char*)d_ws);
  const bool big = ws_size >= fixed + (size_t)B_TOK * KTOT * 2;

  // 1. convert x to bf16
  cvt_bf16_kernel<<<(B_TOK * D_IN / 8 + 255) / 256, 256, 0, stream>>>(x, (u32*)xb, (long)B_TOK * D_IN);
  // 2. transpose+convert weights to [N,K] bf16 (64x64 tiles)
  transpose_bf16_kernel<<<dim3(D_HID / 64, D_IN / 64, 1), 256, 0, stream>>>(Wg1, (u16*)Wg1t, D_IN, D_HID);
  transpose_bf16_kernel<<<dim3(D_HID / 64, D_IN / 64, NE), 256, 0, stream>>>(W1, (u16*)W1t, D_IN, D_HID);
  transpose_bf16_kernel<<<dim3(D_OUT / 64, KTOT / 64, 1), 256, 0, stream>>>(W2, (u16*)W2t, KTOT, D_OUT);
  // 3. gating L1: g = relu(xb @ Wg1t^T + bg1)   M=4096 N=4096 K=1024
  gemm_mfma256<0><<<dim3(16, 16, 1), 512, 0, stream>>>(xb, Wg1t, bg1, nullptr, g,
                                                       D_IN, (long)D_IN, 0L, (long)D_HID, D_IN / 32, 0);
  // 4. gate = softmax(g @ Wg2 + bg2)
  gate_softmax_kernel<<<B_TOK / 4, 256, 0, stream>>>(g, Wg2, bg2, gate);
  // 5. out = sum_e gate*b2
  gate_bias_kernel<<<B_TOK * D_OUT / 4 / 256, 256, 0, stream>>>(gate, b2, out);

  if (big) {
    // 6. hs[b, e*4096+j] = gate[b,e]*relu(xb @ W1t[e]^T + b1[e])  grid 2048
    gemm_mfma256<1><<<dim3(16, 16, NE), 512, 0, stream>>>(xb, W1t, b1, gate, hs,
                                                          D_IN, (long)D_IN, 0L, (long)KTOT, D_IN / 32, 0);
    // 7. out += hs @ W2flat   M=4096 N=1024 K=32768, split-K=4: grid 256
    gemm_mfma256<2><<<dim3(16, 4, 4), 512, 0, stream>>>(hs, W2t, nullptr, nullptr, out,
                                                        KTOT, (long)KTOT, 0L, (long)D_OUT, KTOT / 4 / 32, 0);
  } else {
    for (int e = 0; e < NE; ++e) {
      gemm_mfma256<1><<<dim3(16, 16, 1), 512, 0, stream>>>(xb, W1t, b1, gate, hs,
                                                           D_IN, (long)D_IN, 0L, (long)D_HID, D_IN / 32, e);
      gemm_mfma256<2><<<dim3(16, 4, 2), 512, 0, stream>>>(hs, W2t, nullptr, nullptr, out,
                                                          D_HID, (long)KTOT, (long)e * D_HID, (long)D_OUT,
                                                          D_HID / 2 / 32, e);
    }
  }
}

// Round 4
// 1005.517 us; speedup vs baseline: 1.0812x; 1.0812x over previous
//
#include <hip/hip_runtime.h>
#include <stdint.h>

typedef __bf16 bf16;
typedef __attribute__((ext_vector_type(8))) __bf16 bf16x8;
typedef __attribute__((ext_vector_type(4))) float f32x4;
typedef unsigned short u16;
typedef unsigned int u32;

#define B_TOK 4096
#define D_IN  1024
#define D_HID 4096
#define D_OUT 1024
#define NE    8
#define KTOT  (NE * D_HID)   // 32768

#define AS1 __attribute__((address_space(1)))
#define AS3 __attribute__((address_space(3)))

// fp32 -> bf16 round-to-nearest-even
__device__ __forceinline__ u16 f2bf(float f) {
  u32 u = __float_as_uint(f);
  return (u16)((u + 0x7FFFu + ((u >> 16) & 1u)) >> 16);
}
__device__ __forceinline__ u32 pack2(float a, float b) {
  return (u32)f2bf(a) | ((u32)f2bf(b) << 16);
}

// ---------------- convert fp32 -> bf16 (contiguous) ----------------
__global__ __launch_bounds__(256) void cvt_bf16_kernel(const float* __restrict__ in,
                                                       u32* __restrict__ out, long n) {
  long i = ((long)blockIdx.x * 256 + threadIdx.x) * 8;
  if (i >= n) return;
  const float4* pf = (const float4*)(in + i);
  float4 f0 = pf[0], f1 = pf[1];
  uint4 o = make_uint4(pack2(f0.x, f0.y), pack2(f0.z, f0.w),
                       pack2(f1.x, f1.y), pack2(f1.z, f1.w));
  *(uint4*)(out + i / 2) = o;
}

// ------- batched transpose + convert: in[z][R][C] f32 -> out[z][C][R] bf16 -------
__global__ __launch_bounds__(256) void transpose_bf16_kernel(const float* __restrict__ in,
                                                             u16* __restrict__ out,
                                                             int R, int C) {
  __shared__ u16 tileT[64][68];   // [col-of-in][row-of-in]
  const size_t bo = (size_t)blockIdx.z * R * C;
  const int c0 = blockIdx.x * 64, r0 = blockIdx.y * 64;
  const int tid = threadIdx.x;
  const int lr = tid >> 4;           // 0..15
  const int lc = (tid & 15) * 4;     // 0..60
#pragma unroll
  for (int p = 0; p < 4; ++p) {
    const int r = p * 16 + lr;
    const float4 v = *(const float4*)(in + bo + (size_t)(r0 + r) * C + c0 + lc);
    tileT[lc + 0][r] = f2bf(v.x);
    tileT[lc + 1][r] = f2bf(v.y);
    tileT[lc + 2][r] = f2bf(v.z);
    tileT[lc + 3][r] = f2bf(v.w);
  }
  __syncthreads();
  const int oc  = tid >> 3;          // 0..31
  const int och = (tid & 7) * 8;     // 0..56
#pragma unroll
  for (int p = 0; p < 2; ++p) {
    const int c = p * 32 + oc;
    bf16x8 v = *(const bf16x8*)(&tileT[c][och]);
    *(bf16x8*)(out + bo + (size_t)(c0 + c) * R + r0 + och) = v;
  }
}

// ---------------- 256x256 MFMA GEMM, BK=64, one barrier per K-tile ----------------
// C[m,n] (+)= sum_k A[m,k] * Bt[n,k]
// MODE 0: gating L1  : C = bf16( relu(acc + bias[n]) ),               grid (16,16,1)
// MODE 1: expert L1  : C = bf16( gate[m,e] * relu(acc + bias[e,n]) ), grid (16,16,E)
// MODE 2: final      : atomicAdd fp32 C += acc (split-K over z),      grid (16,4,8)
// 512 thr = 8 waves (2M x 4N), per-wave output 128x64, acc 8x4 f32x4.
// LDS 128 KB: 2 bufs x (A 256x64 | B 256x64) bf16 -> 1 block/CU.
// K-loop per tile t (64 MFMA/wave between barriers):
//   vmcnt(0)  [tile-t staging done; issued a FULL tile earlier -> ~2500cy cover, no stall]
//   s_barrier [one barrier per tile: readers of buf(t-1) all done -> buf flip safe]
//   issue gload(t+1) -> other buf
//   k-half0: 12 ds_read_b128 -> 32 MFMA; k-half1: 12 ds_read -> 32 MFMA
//   (compiler interleaves lgkmcnt finely; reads of k1 overlap MFMA of k0)
// XOR swizzle (R2-verified, ~0 conflicts): LDS chunk slot = global chunk ^ (row&7),
// folded into the staging lane->global map; reads use the same involution.
// Block order: DEFAULT (no swizzle). Dispatch order already gives per-round L3
// locality: MODE1 round = one expert (16 MB), MODE2 split-8 round = half k-slice.
template<int MODE>
__global__ __launch_bounds__(512, 2) void gemm_mfma256(
    const bf16* __restrict__ A,
    const bf16* __restrict__ Bt,
    const float* __restrict__ bias,
    const float* __restrict__ gate,
    void* __restrict__ Cptr,
    int K, long ldB, long kOffB, long ldC, int kIters, int eArg)
{
  __shared__ __align__(16) bf16 smem[65536];   // 128 KB = 2 x 64KB buffers

  const int tid  = threadIdx.x;
  const int wave = tid >> 6;
  const int lane = tid & 63;
  const int quad = lane >> 4;
  const int l16  = lane & 15;
  const int wr = (wave >> 2) * 128;   // wave row base in 256-tile
  const int wc = (wave & 3) * 64;     // wave col base

  const int m0 = blockIdx.x * 256;
  const int n0 = blockIdx.y * 256;

  int expert = 0;
  long cColOff = 0;
  const bf16* Bp = Bt;
  const float* biasP = bias;
  if (MODE == 1) {
    if (gridDim.z > 1) { expert = blockIdx.z; cColOff = (long)expert * D_HID; }
    else               { expert = eArg; }
    Bp = Bt + (size_t)expert * D_HID * (size_t)ldB;
    biasP = bias + (size_t)expert * D_HID;
  }
  const int nt = kIters;                                   // K-tiles of 64
  const long kBase = (MODE == 2) ? (long)blockIdx.z * nt * 64 : 0;

  // staging: each gload instr = 64 lanes x 16B = 8 rows x 128B.
  // lane -> row (lane>>3), LDS chunk lane&7; global chunk = (lane&7) ^ row.
  const int sRow = lane >> 3;                      // 0..7
  const int sCol = ((lane & 7) ^ sRow) * 8;        // pre-swizzled global k-chunk

  const bf16* aSrc = A  + (size_t)(m0 + wave * 8 + sRow) * K   + kBase + sCol;
  const bf16* bSrc = Bp + (size_t)(n0 + wave * 8 + sRow) * ldB + kOffB + kBase + sCol;
  const int dOff = (wave * 8) * 64;                // wave's dst row offset (elems)

  f32x4 acc[8][4];
#pragma unroll
  for (int i = 0; i < 8; ++i)
#pragma unroll
    for (int j = 0; j < 4; ++j)
      acc[i][j] = (f32x4){0.f, 0.f, 0.f, 0.f};

#define GLL(tt, bb) do { \
    bf16* dstA = smem + (bb) * 32768 + dOff; \
    bf16* dstB = dstA + 16384; \
    const bf16* srcA = aSrc + (size_t)(tt) * 64; \
    const bf16* srcB = bSrc + (size_t)(tt) * 64; \
    _Pragma("unroll") \
    for (int g_ = 0; g_ < 4; ++g_) { \
      __builtin_amdgcn_global_load_lds((AS1 void*)(srcA + (size_t)g_ * 64 * K), \
                                       (AS3 void*)(dstA + g_ * 64 * 64), 16, 0, 0); \
      __builtin_amdgcn_global_load_lds((AS1 void*)(srcB + (size_t)g_ * 64 * ldB), \
                                       (AS3 void*)(dstB + g_ * 64 * 64), 16, 0, 0); \
    } \
  } while (0)

  // prologue: stage tile 0 into buffer 0
  GLL(0, 0);

  for (int t = 0; t < nt; ++t) {
    const bf16* Ab = smem + (t & 1) * 32768;
    const bf16* Bb = Ab + 16384;
    asm volatile("s_waitcnt vmcnt(0)" ::: "memory");
    __builtin_amdgcn_s_barrier();
    if (t + 1 < nt) GLL(t + 1, (t + 1) & 1);
#pragma unroll
    for (int kh = 0; kh < 2; ++kh) {
      const int sw = (((kh << 2) + quad) ^ (l16 & 7)) << 3;
      bf16x8 bv[4], av[8];
#pragma unroll
      for (int j = 0; j < 4; ++j)
        bv[j] = *(const bf16x8*)(Bb + (wc + j * 16 + l16) * 64 + sw);
#pragma unroll
      for (int i = 0; i < 8; ++i)
        av[i] = *(const bf16x8*)(Ab + (wr + i * 16 + l16) * 64 + sw);
      __builtin_amdgcn_s_setprio(1);
#pragma unroll
      for (int i = 0; i < 8; ++i)
#pragma unroll
        for (int j = 0; j < 4; ++j)
          acc[i][j] = __builtin_amdgcn_mfma_f32_16x16x32_bf16(av[i], bv[j], acc[i][j], 0, 0, 0);
      __builtin_amdgcn_s_setprio(0);
    }
  }
#undef GLL

  // epilogue: C/D layout col = lane&15, row = quad*4 + reg
  if (MODE <= 1) {
    const int SL = 72;
    u16* slab = (u16*)smem + wave * (16 * SL);
    u16* C = (u16*)Cptr;
    float bv[4];
#pragma unroll
    for (int j = 0; j < 4; ++j) bv[j] = biasP[n0 + wc + j * 16 + l16];
#pragma unroll
    for (int i = 0; i < 8; ++i) {
#pragma unroll
      for (int r = 0; r < 4; ++r) {
        const int lrow = quad * 4 + r;
        float sc = 1.0f;
        if (MODE == 1) sc = gate[(size_t)(m0 + wr + i * 16 + lrow) * NE + expert];
#pragma unroll
        for (int j = 0; j < 4; ++j) {
          float v = fmaxf(acc[i][j][r] + bv[j], 0.0f) * sc;
          slab[lrow * SL + j * 16 + l16] = f2bf(v);
        }
      }
      const int rrow = lane & 15;
      const int c0c  = lane >> 4;
      bf16x8 v0 = *(const bf16x8*)(slab + rrow * SL + c0c * 8);
      bf16x8 v1 = *(const bf16x8*)(slab + rrow * SL + (c0c + 4) * 8);
      u16* orow = C + (size_t)(m0 + wr + i * 16 + rrow) * ldC + cColOff + n0 + wc;
      *(bf16x8*)(orow + c0c * 8)       = v0;
      *(bf16x8*)(orow + (c0c + 4) * 8) = v1;
    }
  } else {
    float* C = (float*)Cptr;
#pragma unroll
    for (int i = 0; i < 8; ++i) {
#pragma unroll
      for (int r = 0; r < 4; ++r) {
        const int row = m0 + wr + i * 16 + quad * 4 + r;
        float* crow = C + (size_t)row * ldC + n0 + wc + l16;
#pragma unroll
        for (int j = 0; j < 4; ++j)
          atomicAdd(crow + j * 16, acc[i][j][r]);
      }
    }
  }
}

// ---------------- gating layer 2 + softmax: one wave per row ----------------
__global__ __launch_bounds__(256) void gate_softmax_kernel(const bf16* __restrict__ g,
                                                           const float* __restrict__ Wg2,
                                                           const float* __restrict__ bg2,
                                                           float* __restrict__ gate) {
  const int wave = threadIdx.x >> 6, lane = threadIdx.x & 63;
  const int row = blockIdx.x * 4 + wave;
  const bf16* gr = g + (size_t)row * D_HID;
  float acc[NE];
#pragma unroll
  for (int e = 0; e < NE; ++e) acc[e] = 0.f;
  for (int k = lane; k < D_HID; k += 64) {
    const float gv = (float)gr[k];
    const float* w = Wg2 + (size_t)k * NE;
#pragma unroll
    for (int e = 0; e < NE; ++e) acc[e] += gv * w[e];
  }
#pragma unroll
  for (int e = 0; e < NE; ++e) {
    float v = acc[e];
#pragma unroll
    for (int off = 32; off > 0; off >>= 1) v += __shfl_down(v, off);
    acc[e] = v;
  }
  if (lane == 0) {
    float mx = -3.4e38f;
#pragma unroll
    for (int e = 0; e < NE; ++e) { acc[e] += bg2[e]; mx = fmaxf(mx, acc[e]); }
    float s = 0.f;
#pragma unroll
    for (int e = 0; e < NE; ++e) { acc[e] = __expf(acc[e] - mx); s += acc[e]; }
    const float inv = 1.f / s;
#pragma unroll
    for (int e = 0; e < NE; ++e) gate[(size_t)row * NE + e] = acc[e] * inv;
  }
}

// ---------------- out = sum_e gate[b,e] * b2[e,o]  (WRITES out) -------------
__global__ __launch_bounds__(256) void gate_bias_kernel(const float* __restrict__ gate,
                                                        const float* __restrict__ b2,
                                                        float* __restrict__ out) {
  const int idx = blockIdx.x * 256 + threadIdx.x;
  const int b = idx >> 8;
  const int o = (idx & 255) * 4;
  float4 v = {0.f, 0.f, 0.f, 0.f};
#pragma unroll
  for (int e = 0; e < NE; ++e) {
    const float gv = gate[(size_t)b * NE + e];
    const float4 bb = *(const float4*)(b2 + (size_t)e * D_OUT + o);
    v.x += gv * bb.x; v.y += gv * bb.y; v.z += gv * bb.z; v.w += gv * bb.w;
  }
  *(float4*)(out + (size_t)b * D_OUT + o) = v;
}

extern "C" void kernel_launch(void* const* d_in, const int* in_sizes, int n_in,
                              void* d_out, int out_size, void* d_ws, size_t ws_size,
                              hipStream_t stream) {
  const float* x   = (const float*)d_in[0];   // [4096,1024]
  const float* W1  = (const float*)d_in[1];   // [8,1024,4096]
  const float* b1  = (const float*)d_in[2];   // [8,4096]
  const float* W2  = (const float*)d_in[3];   // [8,4096,1024] == [32768,1024]
  const float* b2  = (const float*)d_in[4];   // [8,1024]
  const float* Wg1 = (const float*)d_in[5];   // [1024,4096]
  const float* bg1 = (const float*)d_in[6];   // [4096]
  const float* Wg2 = (const float*)d_in[7];   // [4096,8]
  const float* bg2 = (const float*)d_in[8];   // [8]
  float* out = (float*)d_out;                 // [4096,1024] fp32

  char* p = (char*)d_ws;
  bf16* xb   = (bf16*)p; p += (size_t)B_TOK * D_IN * 2;        //  8.4 MB
  bf16* Wg1t = (bf16*)p; p += (size_t)D_HID * D_IN * 2;        //  8.4 MB [4096,1024]
  bf16* W1t  = (bf16*)p; p += (size_t)NE * D_HID * D_IN * 2;   // 67 MB   [8][4096,1024]
  bf16* W2t  = (bf16*)p; p += (size_t)D_OUT * KTOT * 2;        // 67 MB   [1024,32768]
  bf16* g    = (bf16*)p; p += (size_t)B_TOK * D_HID * 2;       // 33.5 MB
  float* gate= (float*)p; p += (size_t)B_TOK * NE * 4;         //  0.13 MB
  bf16* hs   = (bf16*)p;                                       // big: 268 MB / small: 33.5 MB
  const size_t fixed = (size_t)(p - (char*)d_ws);
  const bool big = ws_size >= fixed + (size_t)B_TOK * KTOT * 2;

  // 1. convert x to bf16
  cvt_bf16_kernel<<<(B_TOK * D_IN / 8 + 255) / 256, 256, 0, stream>>>(x, (u32*)xb, (long)B_TOK * D_IN);
  // 2. transpose+convert weights to [N,K] bf16 (64x64 tiles)
  transpose_bf16_kernel<<<dim3(D_HID / 64, D_IN / 64, 1), 256, 0, stream>>>(Wg1, (u16*)Wg1t, D_IN, D_HID);
  transpose_bf16_kernel<<<dim3(D_HID / 64, D_IN / 64, NE), 256, 0, stream>>>(W1, (u16*)W1t, D_IN, D_HID);
  transpose_bf16_kernel<<<dim3(D_OUT / 64, KTOT / 64, 1), 256, 0, stream>>>(W2, (u16*)W2t, KTOT, D_OUT);
  // 3. gating L1: g = relu(xb @ Wg1t^T + bg1)   M=4096 N=4096 K=1024
  gemm_mfma256<0><<<dim3(16, 16, 1), 512, 0, stream>>>(xb, Wg1t, bg1, nullptr, g,
                                                       D_IN, (long)D_IN, 0L, (long)D_HID, D_IN / 64, 0);
  // 4. gate = softmax(g @ Wg2 + bg2)
  gate_softmax_kernel<<<B_TOK / 4, 256, 0, stream>>>(g, Wg2, bg2, gate);
  // 5. out = sum_e gate*b2
  gate_bias_kernel<<<B_TOK * D_OUT / 4 / 256, 256, 0, stream>>>(gate, b2, out);

  if (big) {
    // 6. hs[b, e*4096+j] = gate[b,e]*relu(xb @ W1t[e]^T + b1[e])  grid 2048:
    //    default order -> each 256-block round = one expert (16 MB working set)
    gemm_mfma256<1><<<dim3(16, 16, NE), 512, 0, stream>>>(xb, W1t, b1, gate, hs,
                                                          D_IN, (long)D_IN, 0L, (long)KTOT, D_IN / 64, 0);
    // 7. out += hs @ W2flat   M=4096 N=1024 K=32768, split-K=8: grid 512 = 2 rounds,
    //    each round's working set = half hs (134 MB) + half W2t (34 MB) -> L3-fit
    gemm_mfma256<2><<<dim3(16, 4, 8), 512, 0, stream>>>(hs, W2t, nullptr, nullptr, out,
                                                        KTOT, (long)KTOT, 0L, (long)D_OUT, KTOT / 8 / 64, 0);
  } else {
    for (int e = 0; e < NE; ++e) {
      gemm_mfma256<1><<<dim3(16, 16, 1), 512, 0, stream>>>(xb, W1t, b1, gate, hs,
                                                           D_IN, (long)D_IN, 0L, (long)D_HID, D_IN / 64, e);
      gemm_mfma256<2><<<dim3(16, 4, 2), 512, 0, stream>>>(hs, W2t, nullptr, nullptr, out,
                                                          D_HID, (long)KTOT, (long)e * D_HID, (long)D_OUT,
                                                          D_HID / 2 / 64, e);
    }
  }
}